// Round 5
// baseline (46.639 us; speedup 1.0000x reference)
//
#include <hip/hip_runtime.h>
#include <math.h>

#define BS 256          // big-kernel block size
#define NB 2048         // big-kernel grid
#define NWAVES (BS / 64)
#define TBS 1024        // final-fold block size
#define TNW (TBS / 64)

// ---------- wave reduction helpers ----------
__device__ inline double wred_sum(double v) {
#pragma unroll
    for (int o = 32; o > 0; o >>= 1) v += __shfl_down(v, o, 64);
    return v;
}
__device__ inline float wred_min(float v) {
#pragma unroll
    for (int o = 32; o > 0; o >>= 1) v = fminf(v, __shfl_down(v, o, 64));
    return v;
}
__device__ inline float wred_max(float v) {
#pragma unroll
    for (int o = 32; o > 0; o >>= 1) v = fmaxf(v, __shfl_down(v, o, 64));
    return v;
}

// ---------- pass 1: per-block {sum, sumsq, min, max} over targets ----------
// Plain scattered stores; coherence comes from the dispatch boundary.
__global__ void __launch_bounds__(BS) k_stats(
        const float* __restrict__ t, int n,
        double* __restrict__ bsum, double* __restrict__ bss,
        float* __restrict__ bmn, float* __restrict__ bmx) {
    int tid = blockIdx.x * BS + threadIdx.x;
    const int stride = NB * BS;
    int n4 = n >> 2;
    const float4* t4 = (const float4*)t;

    double s = 0.0, ss = 0.0;
    float mn = 3.4e38f, mx = -3.4e38f;
    int i = tid;
    for (; i + stride < n4; i += 2 * stride) {      // ILP x2: two independent streams
        float4 a = t4[i];
        float4 b = t4[i + stride];
        mn = fminf(mn, fminf(fminf(a.x, a.y), fminf(a.z, a.w)));
        mx = fmaxf(mx, fmaxf(fmaxf(a.x, a.y), fmaxf(a.z, a.w)));
        s += (double)a.x + (double)a.y + (double)a.z + (double)a.w;
        ss += (double)a.x * a.x + (double)a.y * a.y
            + (double)a.z * a.z + (double)a.w * a.w;
        mn = fminf(mn, fminf(fminf(b.x, b.y), fminf(b.z, b.w)));
        mx = fmaxf(mx, fmaxf(fmaxf(b.x, b.y), fmaxf(b.z, b.w)));
        s += (double)b.x + (double)b.y + (double)b.z + (double)b.w;
        ss += (double)b.x * b.x + (double)b.y * b.y
            + (double)b.z * b.z + (double)b.w * b.w;
    }
    for (; i < n4; i += stride) {
        float4 a = t4[i];
        mn = fminf(mn, fminf(fminf(a.x, a.y), fminf(a.z, a.w)));
        mx = fmaxf(mx, fmaxf(fmaxf(a.x, a.y), fmaxf(a.z, a.w)));
        s += (double)a.x + (double)a.y + (double)a.z + (double)a.w;
        ss += (double)a.x * a.x + (double)a.y * a.y
            + (double)a.z * a.z + (double)a.w * a.w;
    }
    if (tid == 0) {  // scalar tail (n % 4), robustness only
        for (int j = (n4 << 2); j < n; j++) {
            float v = t[j];
            mn = fminf(mn, v); mx = fmaxf(mx, v);
            s += v; ss += (double)v * v;
        }
    }

    s = wred_sum(s); ss = wred_sum(ss); mn = wred_min(mn); mx = wred_max(mx);

    __shared__ double sh_s[NWAVES], sh_ss[NWAVES];
    __shared__ float sh_mn[NWAVES], sh_mx[NWAVES];
    int wid = threadIdx.x >> 6, lane = threadIdx.x & 63;
    if (lane == 0) { sh_s[wid] = s; sh_ss[wid] = ss; sh_mn[wid] = mn; sh_mx[wid] = mx; }
    __syncthreads();
    if (threadIdx.x == 0) {
        double S = sh_s[0], SS = sh_ss[0];
        float MN = sh_mn[0], MX = sh_mx[0];
        for (int k = 1; k < NWAVES; k++) {
            S += sh_s[k]; SS += sh_ss[k];
            MN = fminf(MN, sh_mn[k]); MX = fmaxf(MX, sh_mx[k]);
        }
        bsum[blockIdx.x] = S; bss[blockIdx.x] = SS;
        bmn[blockIdx.x] = MN; bmx[blockIdx.x] = MX;
    }
}

// ---------- pass 2: redundant stats fold + weighted L1 partials ----------
__device__ inline float welem(float g, float x, float gmin, float m1, float m2,
                              float sl, float sm, float shv) {
    float w = (g <= m1) ? (g - gmin) * sl
            : (g <= m2) ? (g - m1) * sm + 0.2f
                        : (g - m2) * shv + 0.7f;
    return fabsf(g - x) * w;
}

__global__ void __launch_bounds__(BS) k_loss(
        const float* __restrict__ x, const float* __restrict__ t, int n,
        const double* __restrict__ sbsum, const double* __restrict__ sbss,
        const float* __restrict__ sbmn, const float* __restrict__ sbmx,
        double* __restrict__ bsum) {
    // --- every block folds the 2048 stats partials itself (L2-warm, 48 KB).
    // Identical fold order in every block -> bitwise-identical stats. ---
    __shared__ double sh_s[NWAVES], sh_ss[NWAVES];
    __shared__ float sh_mn[NWAVES], sh_mx[NWAVES];
    __shared__ float s_c[8];   // gmin, m1, m2, sl, sm, sh
    {
        double s = 0.0, ss = 0.0;
        float mn = 3.4e38f, mx = -3.4e38f;
        for (int i = threadIdx.x; i < NB; i += BS) {
            s += sbsum[i]; ss += sbss[i];
            mn = fminf(mn, sbmn[i]); mx = fmaxf(mx, sbmx[i]);
        }
        s = wred_sum(s); ss = wred_sum(ss); mn = wred_min(mn); mx = wred_max(mx);
        int wid = threadIdx.x >> 6, lane = threadIdx.x & 63;
        if (lane == 0) { sh_s[wid] = s; sh_ss[wid] = ss; sh_mn[wid] = mn; sh_mx[wid] = mx; }
        __syncthreads();
        if (threadIdx.x == 0) {
            double S = sh_s[0], SS = sh_ss[0];
            float MN = sh_mn[0], MX = sh_mx[0];
            for (int k = 1; k < NWAVES; k++) {
                S += sh_s[k]; SS += sh_ss[k];
                MN = fminf(MN, sh_mn[k]); MX = fmaxf(MX, sh_mx[k]);
            }
            double dn = (double)n;
            double mean = S / dn;
            double var = (SS - S * S / dn) / (dn - 1.0);   // ddof=1
            double sd = sqrt(var);
            float m1 = (float)(mean + sd);
            float m2 = (float)(mean + 3.0 * sd);
            s_c[0] = MN;                  // gmin
            s_c[1] = m1;
            s_c[2] = m2;
            s_c[3] = 0.2f / (m1 - MN);    // low slope
            s_c[4] = 0.5f / (m2 - m1);    // mid slope
            s_c[5] = 0.3f / (MX - m2);    // high slope
        }
        __syncthreads();
    }
    float gmin = s_c[0], m1 = s_c[1], m2 = s_c[2];
    float sl = s_c[3], sm = s_c[4], shv = s_c[5];

    int tid = blockIdx.x * BS + threadIdx.x;
    const int stride = NB * BS;
    int n4 = n >> 2;
    const float4* x4 = (const float4*)x;
    const float4* t4 = (const float4*)t;

    double acc = 0.0;
    int i = tid;
    for (; i + stride < n4; i += 2 * stride) {      // ILP x2
        float4 tv = t4[i], xv = x4[i];
        float4 tw = t4[i + stride], xw = x4[i + stride];
        float e0 = welem(tv.x, xv.x, gmin, m1, m2, sl, sm, shv);
        float e1 = welem(tv.y, xv.y, gmin, m1, m2, sl, sm, shv);
        float e2 = welem(tv.z, xv.z, gmin, m1, m2, sl, sm, shv);
        float e3 = welem(tv.w, xv.w, gmin, m1, m2, sl, sm, shv);
        acc += (double)e0 + (double)e1 + (double)e2 + (double)e3;
        float f0 = welem(tw.x, xw.x, gmin, m1, m2, sl, sm, shv);
        float f1 = welem(tw.y, xw.y, gmin, m1, m2, sl, sm, shv);
        float f2 = welem(tw.z, xw.z, gmin, m1, m2, sl, sm, shv);
        float f3 = welem(tw.w, xw.w, gmin, m1, m2, sl, sm, shv);
        acc += (double)f0 + (double)f1 + (double)f2 + (double)f3;
    }
    for (; i < n4; i += stride) {
        float4 tv = t4[i], xv = x4[i];
        float e0 = welem(tv.x, xv.x, gmin, m1, m2, sl, sm, shv);
        float e1 = welem(tv.y, xv.y, gmin, m1, m2, sl, sm, shv);
        float e2 = welem(tv.z, xv.z, gmin, m1, m2, sl, sm, shv);
        float e3 = welem(tv.w, xv.w, gmin, m1, m2, sl, sm, shv);
        acc += (double)e0 + (double)e1 + (double)e2 + (double)e3;
    }
    if (tid == 0) {  // scalar tail
        for (int j = (n4 << 2); j < n; j++)
            acc += (double)welem(t[j], x[j], gmin, m1, m2, sl, sm, shv);
    }

    acc = wred_sum(acc);
    __shared__ double sh_acc[NWAVES];
    int wid = threadIdx.x >> 6, lane = threadIdx.x & 63;
    if (lane == 0) sh_acc[wid] = acc;
    __syncthreads();
    if (threadIdx.x == 0) {
        double S = sh_acc[0];
        for (int k = 1; k < NWAVES; k++) S += sh_acc[k];
        bsum[blockIdx.x] = S;
    }
}

// ---------- pass 3: final mean ----------
__global__ void __launch_bounds__(TBS) k_final(
        const double* __restrict__ bsum, long long n, float* __restrict__ out) {
    double s = 0.0;
    for (int i = threadIdx.x; i < NB; i += TBS) s += bsum[i];
    s = wred_sum(s);
    __shared__ double sh_s[TNW];
    int wid = threadIdx.x >> 6, lane = threadIdx.x & 63;
    if (lane == 0) sh_s[wid] = s;
    __syncthreads();
    if (threadIdx.x == 0) {
        double S = sh_s[0];
        for (int i = 1; i < TNW; i++) S += sh_s[i];
        out[0] = (float)(S / (double)n);
    }
}

extern "C" void kernel_launch(void* const* d_in, const int* in_sizes, int n_in,
                              void* d_out, int out_size, void* d_ws, size_t ws_size,
                              hipStream_t stream) {
    const float* inp = (const float*)d_in[0];
    const float* tgt = (const float*)d_in[1];
    int n = in_sizes[0];

    // workspace layout (bytes); plain stores -> no init needed:
    //   [0,      16384) double sum1[NB]
    //   [16384,  32768) double ss1[NB]
    //   [32768,  40960) float  mn1[NB]
    //   [40960,  49152) float  mx1[NB]
    //   [49280,  65664) double sum2[NB]
    char* ws = (char*)d_ws;
    double* sum1  = (double*)(ws);
    double* ss1   = (double*)(ws + 16384);
    float*  mn1   = (float*)(ws + 32768);
    float*  mx1   = (float*)(ws + 40960);
    double* sum2  = (double*)(ws + 49280);

    k_stats<<<NB, BS, 0, stream>>>(tgt, n, sum1, ss1, mn1, mx1);
    k_loss<<<NB, BS, 0, stream>>>(inp, tgt, n, sum1, ss1, mn1, mx1, sum2);
    k_final<<<1, TBS, 0, stream>>>(sum2, (long long)n, (float*)d_out);
}